// Round 2
// baseline (745.637 us; speedup 1.0000x reference)
//
#include <hip/hip_runtime.h>
#include <hip/hip_fp16.h>
#include <math.h>

typedef _Float16 half_t;
typedef half_t half4_t __attribute__((ext_vector_type(4)));
typedef half_t half8_t __attribute__((ext_vector_type(8)));
typedef float f32x4 __attribute__((ext_vector_type(4)));

#define LN_EPS 1e-5f

// ---------------------------------------------------------------------------
// Pack W*g (LN gain folded in) into f16 MFMA B-fragment order:
//   packed[((cbg*T + t)*64 + l)*8 + j] = (f16)(W[16*cbg+(l&15)][32t+8*(l>>4)+j] * g[k])
// Slot counts: W0: 32*24*64=49152, W1: 16*16*64=16384, W2: 8*8*64=4096.
// ---------------------------------------------------------------------------
__global__ void pack_weights(const float* __restrict__ W0, const float* __restrict__ g0,
                             const float* __restrict__ W1, const float* __restrict__ g1,
                             const float* __restrict__ W2, const float* __restrict__ g2,
                             half_t* __restrict__ ws) {
    int sid = blockIdx.x * 256 + threadIdx.x;
    const float* W; const float* g; int K, T, off;
    if (sid < 49152)      { W = W0; g = g0; K = 768; T = 24; off = 0; }
    else if (sid < 65536) { W = W1; g = g1; K = 512; T = 16; off = 49152; sid -= 49152; }
    else if (sid < 69632) { W = W2; g = g2; K = 256; T = 8;  off = 65536; sid -= 65536; }
    else return;
    const int l   = sid & 63;
    const int t   = (sid >> 6) % T;
    const int cbg = (sid >> 6) / T;
    const int n   = (l & 15) + 16 * cbg;
    const int k0  = 32 * t + 8 * (l >> 4);
    const float* src = W + (size_t)n * K + k0;
    const float* gs  = g + k0;
    half8_t v;
    #pragma unroll
    for (int jq = 0; jq < 8; jq++) v[jq] = (half_t)(src[jq] * gs[jq]);
    *(half8_t*)(ws + (size_t)(off + sid) * 8) = v;
}

// ---------------------------------------------------------------------------
// Fold LN bias into per-output scalars: s[n] = sum_k W[n,k]*g[k],
// c'[n] = sum_k W[n,k]*b[k] + c[n]. One wave per output n. Layer3 scalars too.
// f layout: s0[512] c0[512] s1[256] c1[256] s2[128] c2[128] w3g[128] s3 c3'
// ---------------------------------------------------------------------------
__global__ void fold_bias(const float* __restrict__ W0, const float* __restrict__ g0,
                          const float* __restrict__ b0, const float* __restrict__ c0,
                          const float* __restrict__ W1, const float* __restrict__ g1,
                          const float* __restrict__ b1, const float* __restrict__ c1,
                          const float* __restrict__ W2, const float* __restrict__ g2,
                          const float* __restrict__ b2, const float* __restrict__ c2,
                          const float* __restrict__ W3, const float* __restrict__ g3,
                          const float* __restrict__ b3, const float* __restrict__ c3,
                          float* __restrict__ f) {
    const int gw   = (blockIdx.x * 256 + threadIdx.x) >> 6;
    const int lane = threadIdx.x & 63;
    if (gw == 896) {
        float s = 0.f, cb_ = 0.f;
        for (int k = lane; k < 128; k += 64) {
            const float wg = W3[k] * g3[k];
            f[1792 + k] = wg;
            s += wg; cb_ += W3[k] * b3[k];
        }
        #pragma unroll
        for (int m = 1; m < 64; m <<= 1) { s += __shfl_xor(s, m); cb_ += __shfl_xor(cb_, m); }
        if (lane == 0) { f[1920] = s; f[1921] = cb_ + c3[0]; }
        return;
    }
    const float *W, *g, *b, *cc; int K, n; float *sf, *cf;
    if (gw < 512)      { W = W0; g = g0; b = b0; cc = c0; K = 768; n = gw;       sf = f;        cf = f + 512; }
    else if (gw < 768) { W = W1; g = g1; b = b1; cc = c1; K = 512; n = gw - 512; sf = f + 1024; cf = f + 1280; }
    else if (gw < 896) { W = W2; g = g2; b = b2; cc = c2; K = 256; n = gw - 768; sf = f + 1536; cf = f + 1664; }
    else return;
    const float* Wr = W + (size_t)n * K;
    float s = 0.f, cb_ = 0.f;
    for (int k = lane; k < K; k += 64) { const float wg = Wr[k] * g[k]; s += wg; cb_ += Wr[k] * b[k]; }
    #pragma unroll
    for (int m = 1; m < 64; m <<= 1) { s += __shfl_xor(s, m); cb_ += __shfl_xor(cb_, m); }
    if (lane == 0) { sf[n] = s; cf[n] = cb_ + cc[n]; }
}

// ---------------------------------------------------------------------------
// Fused MLP: 32 rows/block, 256 threads (4 waves). LN folded into weights:
// GEMMs run on RAW f16 activations; LN applied as epilogue rs*(acc - m*s)+c'.
// ---------------------------------------------------------------------------
__global__ __launch_bounds__(256, 4)
void fused_mlp(const float* __restrict__ x_in,
               const half_t* __restrict__ W0p, const half_t* __restrict__ W1p,
               const half_t* __restrict__ W2p, const float* __restrict__ f,
               float* __restrict__ out)
{
    __shared__ half_t frag[16384];                     // 32 KiB
    __shared__ float psum[4][32], psq[4][32], pdot[4][32];
    __shared__ float row_m[32], row_rs[32];

    const int tid  = threadIdx.x;
    const int lane = tid & 63;
    const int wv   = tid >> 6;       // 0..3
    const int grp  = lane >> 4;      // 0..3
    const int cl   = lane & 15;
    const int row  = tid >> 3;       // 0..31 (staging row)
    const int jj   = tid & 7;
    const long r0  = (long)blockIdx.x * 32;
    const float* xrow = x_in + (r0 + row) * 768;

    const int rb_w   = row >> 4;
    const int slot_w = (row & 15) + 16 * (jj >> 1);
    const int jo     = 4 * (jj & 1);

    const float* s0f = f;        const float* c0f = f + 512;
    const float* s1f = f + 1024; const float* c1f = f + 1280;
    const float* s2f = f + 1536; const float* c2f = f + 1664;
    const float* w3f = f + 1792;

    float s = 0.f, ss = 0.f;     // LN0 stats accumulated during staging

    // stage K-chunk c (256 cols) of raw x as f16 fragments into buf[c&1]
    auto stage = [&](int c) {
        half_t* fb = frag + 8192 * (c & 1);
        const float* xp = xrow + 256 * c + 4 * jj;
        #pragma unroll
        for (int i = 0; i < 8; i++) {
            const f32x4 v = __builtin_nontemporal_load((const f32x4*)(xp + 32 * i));
            s  += v[0] + v[1] + v[2] + v[3];
            ss += v[0]*v[0] + v[1]*v[1] + v[2]*v[2] + v[3]*v[3];
            half4_t hv;
            hv[0] = (half_t)v[0]; hv[1] = (half_t)v[1];
            hv[2] = (half_t)v[2]; hv[3] = (half_t)v[3];
            *(half4_t*)(&fb[((i * 2 + rb_w) * 64 + slot_w) * 8 + jo]) = hv;
        }
    };

    f32x4 acc0[2][8];
    #pragma unroll
    for (int rb = 0; rb < 2; rb++)
        #pragma unroll
        for (int cb = 0; cb < 8; cb++) acc0[rb][cb] = 0.f;

    auto gemm0 = [&](int c) {
        const half_t* fb = frag + 8192 * (c & 1);
        #pragma unroll
        for (int i = 0; i < 8; i++) {
            const int t = 8 * c + i;
            const half8_t a0 = *(const half8_t*)(&fb[((i * 2 + 0) * 64 + lane) * 8]);
            const half8_t a1 = *(const half8_t*)(&fb[((i * 2 + 1) * 64 + lane) * 8]);
            #pragma unroll
            for (int cb = 0; cb < 8; cb++) {
                const half8_t bf = *(const half8_t*)(W0p + (size_t)(((8 * wv + cb) * 24 + t) * 64 + lane) * 8);
                acc0[0][cb] = __builtin_amdgcn_mfma_f32_16x16x32_f16(a0, bf, acc0[0][cb], 0, 0, 0);
                acc0[1][cb] = __builtin_amdgcn_mfma_f32_16x16x32_f16(a1, bf, acc0[1][cb], 0, 0, 0);
            }
        }
    };

    stage(0); __syncthreads();
    gemm0(0); stage(1); __syncthreads();
    gemm0(1); stage(2);
    // finalize LN0 stats (all of x read by this thread now)
    s  += __shfl_xor(s, 1);  s  += __shfl_xor(s, 2);  s  += __shfl_xor(s, 4);
    ss += __shfl_xor(ss, 1); ss += __shfl_xor(ss, 2); ss += __shfl_xor(ss, 4);
    if (jj == 0) {
        const float mm = s * (1.f / 768.f);
        row_m[row]  = mm;
        row_rs[row] = 1.f / sqrtf(ss * (1.f / 768.f) - mm * mm + LN_EPS);
    }
    __syncthreads();
    gemm0(2);

    // ---- epilogue0: LN0 fold + ELU + LN1 partial stats ----
    {
        float rm[8], rr[8];
        #pragma unroll
        for (int rb = 0; rb < 2; rb++)
            #pragma unroll
            for (int v = 0; v < 4; v++) {
                rm[rb*4+v] = row_m[16*rb + 4*grp + v];
                rr[rb*4+v] = row_rs[16*rb + 4*grp + v];
            }
        #pragma unroll
        for (int cb = 0; cb < 8; cb++) {
            const int c = cl + 16 * (8 * wv + cb);
            const float sv = s0f[c], cv = c0f[c];
            #pragma unroll
            for (int rb = 0; rb < 2; rb++)
                #pragma unroll
                for (int v = 0; v < 4; v++) {
                    float y = rr[rb*4+v] * (acc0[rb][cb][v] - rm[rb*4+v] * sv) + cv;
                    y = y > 0.f ? y : (__expf(y) - 1.f);
                    acc0[rb][cb][v] = y;
                }
        }
        #pragma unroll
        for (int rb = 0; rb < 2; rb++)
            #pragma unroll
            for (int v = 0; v < 4; v++) {
                float a_ = 0.f, q_ = 0.f;
                #pragma unroll
                for (int cb = 0; cb < 8; cb++) { const float y = acc0[rb][cb][v]; a_ += y; q_ += y * y; }
                a_ += __shfl_xor(a_, 1); a_ += __shfl_xor(a_, 2); a_ += __shfl_xor(a_, 4); a_ += __shfl_xor(a_, 8);
                q_ += __shfl_xor(q_, 1); q_ += __shfl_xor(q_, 2); q_ += __shfl_xor(q_, 4); q_ += __shfl_xor(q_, 8);
                if (cl == 0) { psum[wv][16*rb + 4*grp + v] = a_; psq[wv][16*rb + 4*grp + v] = q_; }
            }
    }
    __syncthreads();

    // ---- write raw x1 fragments (no normalize needed!) + finalize LN1 ----
    #pragma unroll
    for (int cb = 0; cb < 8; cb++) {
        const int c = cl + 16 * (8 * wv + cb);
        const int t = c >> 5, j = c & 7, sc = 16 * ((c >> 3) & 3);
        #pragma unroll
        for (int rb = 0; rb < 2; rb++)
            #pragma unroll
            for (int v = 0; v < 4; v++)
                frag[((t * 2 + rb) * 64 + (4*grp + v + sc)) * 8 + j] = (half_t)acc0[rb][cb][v];
    }
    if (tid < 32) {
        float a_ = 0.f, q_ = 0.f;
        #pragma unroll
        for (int w = 0; w < 4; w++) { a_ += psum[w][tid]; q_ += psq[w][tid]; }
        const float mm = a_ * (1.f / 512.f);
        row_m[tid]  = mm;
        row_rs[tid] = 1.f / sqrtf(q_ * (1.f / 512.f) - mm * mm + LN_EPS);
    }
    __syncthreads();

    // ---- GEMM1: K=512, wave owns 64 cols ----
    f32x4 acc1[2][4];
    #pragma unroll
    for (int rb = 0; rb < 2; rb++)
        #pragma unroll
        for (int cb = 0; cb < 4; cb++) acc1[rb][cb] = 0.f;
    for (int t = 0; t < 16; t++) {
        const half8_t a0 = *(const half8_t*)(&frag[((t * 2 + 0) * 64 + lane) * 8]);
        const half8_t a1 = *(const half8_t*)(&frag[((t * 2 + 1) * 64 + lane) * 8]);
        #pragma unroll
        for (int cb = 0; cb < 4; cb++) {
            const half8_t bf = *(const half8_t*)(W1p + (size_t)(((4 * wv + cb) * 16 + t) * 64 + lane) * 8);
            acc1[0][cb] = __builtin_amdgcn_mfma_f32_16x16x32_f16(a0, bf, acc1[0][cb], 0, 0, 0);
            acc1[1][cb] = __builtin_amdgcn_mfma_f32_16x16x32_f16(a1, bf, acc1[1][cb], 0, 0, 0);
        }
    }

    // ---- epilogue1 + LN2 partials ----
    {
        float rm[8], rr[8];
        #pragma unroll
        for (int rb = 0; rb < 2; rb++)
            #pragma unroll
            for (int v = 0; v < 4; v++) {
                rm[rb*4+v] = row_m[16*rb + 4*grp + v];
                rr[rb*4+v] = row_rs[16*rb + 4*grp + v];
            }
        #pragma unroll
        for (int cb = 0; cb < 4; cb++) {
            const int c = cl + 16 * (4 * wv + cb);
            const float sv = s1f[c], cv = c1f[c];
            #pragma unroll
            for (int rb = 0; rb < 2; rb++)
                #pragma unroll
                for (int v = 0; v < 4; v++) {
                    float y = rr[rb*4+v] * (acc1[rb][cb][v] - rm[rb*4+v] * sv) + cv;
                    y = y > 0.f ? y : (__expf(y) - 1.f);
                    acc1[rb][cb][v] = y;
                }
        }
        #pragma unroll
        for (int rb = 0; rb < 2; rb++)
            #pragma unroll
            for (int v = 0; v < 4; v++) {
                float a_ = 0.f, q_ = 0.f;
                #pragma unroll
                for (int cb = 0; cb < 4; cb++) { const float y = acc1[rb][cb][v]; a_ += y; q_ += y * y; }
                a_ += __shfl_xor(a_, 1); a_ += __shfl_xor(a_, 2); a_ += __shfl_xor(a_, 4); a_ += __shfl_xor(a_, 8);
                q_ += __shfl_xor(q_, 1); q_ += __shfl_xor(q_, 2); q_ += __shfl_xor(q_, 4); q_ += __shfl_xor(q_, 8);
                if (cl == 0) { psum[wv][16*rb + 4*grp + v] = a_; psq[wv][16*rb + 4*grp + v] = q_; }
            }
    }
    __syncthreads();

    // ---- write raw x2 fragments + finalize LN2 ----
    #pragma unroll
    for (int cb = 0; cb < 4; cb++) {
        const int c = cl + 16 * (4 * wv + cb);
        const int t = c >> 5, j = c & 7, sc = 16 * ((c >> 3) & 3);
        #pragma unroll
        for (int rb = 0; rb < 2; rb++)
            #pragma unroll
            for (int v = 0; v < 4; v++)
                frag[((t * 2 + rb) * 64 + (4*grp + v + sc)) * 8 + j] = (half_t)acc1[rb][cb][v];
    }
    if (tid < 32) {
        float a_ = 0.f, q_ = 0.f;
        #pragma unroll
        for (int w = 0; w < 4; w++) { a_ += psum[w][tid]; q_ += psq[w][tid]; }
        const float mm = a_ * (1.f / 256.f);
        row_m[tid]  = mm;
        row_rs[tid] = 1.f / sqrtf(q_ * (1.f / 256.f) - mm * mm + LN_EPS);
    }
    __syncthreads();

    // ---- GEMM2: K=256, wave owns 32 cols ----
    f32x4 acc2[2][2];
    acc2[0][0] = 0.f; acc2[0][1] = 0.f; acc2[1][0] = 0.f; acc2[1][1] = 0.f;
    #pragma unroll
    for (int t = 0; t < 8; t++) {
        const half8_t a0 = *(const half8_t*)(&frag[((t * 2 + 0) * 64 + lane) * 8]);
        const half8_t a1 = *(const half8_t*)(&frag[((t * 2 + 1) * 64 + lane) * 8]);
        #pragma unroll
        for (int cb = 0; cb < 2; cb++) {
            const half8_t bf = *(const half8_t*)(W2p + (size_t)(((2 * wv + cb) * 8 + t) * 64 + lane) * 8);
            acc2[0][cb] = __builtin_amdgcn_mfma_f32_16x16x32_f16(a0, bf, acc2[0][cb], 0, 0, 0);
            acc2[1][cb] = __builtin_amdgcn_mfma_f32_16x16x32_f16(a1, bf, acc2[1][cb], 0, 0, 0);
        }
    }

    // ---- epilogue2 + ELU + LN3 partials + folded W3 dot partials ----
    {
        float rm[8], rr[8];
        #pragma unroll
        for (int rb = 0; rb < 2; rb++)
            #pragma unroll
            for (int v = 0; v < 4; v++) {
                rm[rb*4+v] = row_m[16*rb + 4*grp + v];
                rr[rb*4+v] = row_rs[16*rb + 4*grp + v];
            }
        float w3v[2], s2v[2], c2v[2];
        #pragma unroll
        for (int cb = 0; cb < 2; cb++) {
            const int c = cl + 16 * (2 * wv + cb);
            s2v[cb] = s2f[c]; c2v[cb] = c2f[c]; w3v[cb] = w3f[c];
        }
        #pragma unroll
        for (int rb = 0; rb < 2; rb++)
            #pragma unroll
            for (int v = 0; v < 4; v++) {
                float a_ = 0.f, q_ = 0.f, d_ = 0.f;
                #pragma unroll
                for (int cb = 0; cb < 2; cb++) {
                    float y = rr[rb*4+v] * (acc2[rb][cb][v] - rm[rb*4+v] * s2v[cb]) + c2v[cb];
                    y = y > 0.f ? y : (__expf(y) - 1.f);
                    a_ += y; q_ += y * y; d_ += y * w3v[cb];
                }
                a_ += __shfl_xor(a_, 1); a_ += __shfl_xor(a_, 2); a_ += __shfl_xor(a_, 4); a_ += __shfl_xor(a_, 8);
                q_ += __shfl_xor(q_, 1); q_ += __shfl_xor(q_, 2); q_ += __shfl_xor(q_, 4); q_ += __shfl_xor(q_, 8);
                d_ += __shfl_xor(d_, 1); d_ += __shfl_xor(d_, 2); d_ += __shfl_xor(d_, 4); d_ += __shfl_xor(d_, 8);
                if (cl == 0) {
                    psum[wv][16*rb + 4*grp + v] = a_;
                    psq [wv][16*rb + 4*grp + v] = q_;
                    pdot[wv][16*rb + 4*grp + v] = d_;
                }
            }
    }
    __syncthreads();

    // ---- finalize: LN3 + folded dot -> out ----
    if (tid < 32) {
        float a_ = 0.f, q_ = 0.f, d_ = 0.f;
        #pragma unroll
        for (int w = 0; w < 4; w++) { a_ += psum[w][tid]; q_ += psq[w][tid]; d_ += pdot[w][tid]; }
        const float mm = a_ * (1.f / 128.f);
        const float rs = 1.f / sqrtf(q_ * (1.f / 128.f) - mm * mm + LN_EPS);
        out[r0 + tid] = rs * (d_ - mm * f[1920]) + f[1921];
    }
}

extern "C" void kernel_launch(void* const* d_in, const int* in_sizes, int n_in,
                              void* d_out, int out_size, void* d_ws, size_t ws_size,
                              hipStream_t stream) {
    const float* x  = (const float*)d_in[0];
    const float* g0 = (const float*)d_in[1];
    const float* b0 = (const float*)d_in[2];
    const float* W0 = (const float*)d_in[3];
    const float* c0 = (const float*)d_in[4];
    const float* g1 = (const float*)d_in[5];
    const float* b1 = (const float*)d_in[6];
    const float* W1 = (const float*)d_in[7];
    const float* c1 = (const float*)d_in[8];
    const float* g2 = (const float*)d_in[9];
    const float* b2 = (const float*)d_in[10];
    const float* W2 = (const float*)d_in[11];
    const float* c2 = (const float*)d_in[12];
    const float* g3 = (const float*)d_in[13];
    const float* b3 = (const float*)d_in[14];
    const float* W3 = (const float*)d_in[15];
    const float* c3 = (const float*)d_in[16];

    half_t* ws = (half_t*)d_ws;            // packed weights: 557056 halves
    float*  f  = (float*)(ws + 557056);    // folded scalars: 1922 floats

    pack_weights<<<272, 256, 0, stream>>>(W0, g0, W1, g1, W2, g2, ws);
    fold_bias<<<225, 256, 0, stream>>>(W0, g0, b0, c0, W1, g1, b1, c1,
                                       W2, g2, b2, c2, W3, g3, b3, c3, f);

    const int nrows = in_sizes[0] / 768;   // 262144
    fused_mlp<<<nrows / 32, 256, 0, stream>>>(
        x, ws, ws + 393216, ws + 524288, f, (float*)d_out);
}

// Round 3
// 554.346 us; speedup vs baseline: 1.3451x; 1.3451x over previous
//
#include <hip/hip_runtime.h>
#include <hip/hip_fp16.h>
#include <math.h>

typedef _Float16 half_t;
typedef half_t half4_t __attribute__((ext_vector_type(4)));
typedef half_t half8_t __attribute__((ext_vector_type(8)));
typedef float f32x4 __attribute__((ext_vector_type(4)));

#define LN_EPS 1e-5f

// ---------------------------------------------------------------------------
// Pack W*g (LN gain folded) into f16 MFMA B-fragment order:
//   packed[((cbg*T + t)*64 + l)*8 + j] = (f16)(W[16*cbg+(l&15)][32t+8*(l>>4)+j] * g[k])
// ---------------------------------------------------------------------------
__global__ void pack_weights(const float* __restrict__ W0, const float* __restrict__ g0,
                             const float* __restrict__ W1, const float* __restrict__ g1,
                             const float* __restrict__ W2, const float* __restrict__ g2,
                             half_t* __restrict__ ws) {
    int sid = blockIdx.x * 256 + threadIdx.x;
    const float* W; const float* g; int K, T, off;
    if (sid < 49152)      { W = W0; g = g0; K = 768; T = 24; off = 0; }
    else if (sid < 65536) { W = W1; g = g1; K = 512; T = 16; off = 49152; sid -= 49152; }
    else if (sid < 69632) { W = W2; g = g2; K = 256; T = 8;  off = 65536; sid -= 65536; }
    else return;
    const int l   = sid & 63;
    const int t   = (sid >> 6) % T;
    const int cbg = (sid >> 6) / T;
    const int n   = (l & 15) + 16 * cbg;
    const int k0  = 32 * t + 8 * (l >> 4);
    const float* src = W + (size_t)n * K + k0;
    const float* gs  = g + k0;
    half8_t v;
    #pragma unroll
    for (int jq = 0; jq < 8; jq++) v[jq] = (half_t)(src[jq] * gs[jq]);
    *(half8_t*)(ws + (size_t)(off + sid) * 8) = v;
}

// ---------------------------------------------------------------------------
// Fold LN bias into per-output scalars: s[n]=sum_k W[n,k]*g[k],
// c'[n]=sum_k W[n,k]*b[k]+c[n]. f layout:
// s0[512] c0[512] s1[256] c1[256] s2[128] c2[128] w3g[128] s3 c3'
// ---------------------------------------------------------------------------
__global__ void fold_bias(const float* __restrict__ W0, const float* __restrict__ g0,
                          const float* __restrict__ b0, const float* __restrict__ c0,
                          const float* __restrict__ W1, const float* __restrict__ g1,
                          const float* __restrict__ b1, const float* __restrict__ c1,
                          const float* __restrict__ W2, const float* __restrict__ g2,
                          const float* __restrict__ b2, const float* __restrict__ c2,
                          const float* __restrict__ W3, const float* __restrict__ g3,
                          const float* __restrict__ b3, const float* __restrict__ c3,
                          float* __restrict__ f) {
    const int gw   = (blockIdx.x * 256 + threadIdx.x) >> 6;
    const int lane = threadIdx.x & 63;
    if (gw == 896) {
        float s = 0.f, cb_ = 0.f;
        for (int k = lane; k < 128; k += 64) {
            const float wg = W3[k] * g3[k];
            f[1792 + k] = wg;
            s += wg; cb_ += W3[k] * b3[k];
        }
        #pragma unroll
        for (int m = 1; m < 64; m <<= 1) { s += __shfl_xor(s, m); cb_ += __shfl_xor(cb_, m); }
        if (lane == 0) { f[1920] = s; f[1921] = cb_ + c3[0]; }
        return;
    }
    const float *W, *g, *b, *cc; int K, n; float *sf, *cf;
    if (gw < 512)      { W = W0; g = g0; b = b0; cc = c0; K = 768; n = gw;       sf = f;        cf = f + 512; }
    else if (gw < 768) { W = W1; g = g1; b = b1; cc = c1; K = 512; n = gw - 512; sf = f + 1024; cf = f + 1280; }
    else if (gw < 896) { W = W2; g = g2; b = b2; cc = c2; K = 256; n = gw - 768; sf = f + 1536; cf = f + 1664; }
    else return;
    const float* Wr = W + (size_t)n * K;
    float s = 0.f, cb_ = 0.f;
    for (int k = lane; k < K; k += 64) { const float wg = Wr[k] * g[k]; s += wg; cb_ += Wr[k] * b[k]; }
    #pragma unroll
    for (int m = 1; m < 64; m <<= 1) { s += __shfl_xor(s, m); cb_ += __shfl_xor(cb_, m); }
    if (lane == 0) { sf[n] = s; cf[n] = cb_ + cc[n]; }
}

// ---------------------------------------------------------------------------
// Fused MLP: 128 rows/block, 512 threads (8 waves), 1 block/CU.
// LN folded into weights; B-fragments double-buffer-prefetched from L2;
// x staging split load-early/write-late (T14) so HBM hides under MFMA.
// ---------------------------------------------------------------------------
__global__ __launch_bounds__(512, 2)
void fused_mlp(const float* __restrict__ x_in,
               const half_t* __restrict__ W0p, const half_t* __restrict__ W1p,
               const half_t* __restrict__ W2p, const float* __restrict__ f,
               float* __restrict__ out)
{
    __shared__ half_t frag[65536];                 // 128 KiB (staging bufs alias [0,32K))
    __shared__ float psum[8][128], psq[8][128], pdot[8][128];
    __shared__ float row_m[128], row_rs[128];

    const int tid  = threadIdx.x;
    const int lane = tid & 63;
    const int wv   = tid >> 6;       // wave 0..7
    const int grp  = lane >> 4;
    const int cl   = lane & 15;
    const int row  = tid >> 2;       // staging row 0..127
    const int jj   = tid & 3;        // 4 threads per row
    const int rbw  = row >> 4;
    const long r0  = (long)blockIdx.x * 128;
    const float* xrow = x_in + (r0 + row) * 768;

    const float* s0f = f;        const float* c0f = f + 512;
    const float* s1f = f + 1024; const float* c1f = f + 1280;
    const float* s2f = f + 1536; const float* c2f = f + 1664;
    const float* w3f = f + 1792;

    float s = 0.f, ss = 0.f;
    f32x4 vb[8];

    // issue global loads for K-chunk c (128 cols) into regs
    auto stage_load = [&](int c) {
        const float* xp = xrow + 128 * c + 4 * jj;
        #pragma unroll
        for (int i = 0; i < 8; i++)
            vb[i] = __builtin_nontemporal_load((const f32x4*)(xp + 16 * i));
    };
    // stats + f16 convert + fragment ds_write for chunk c
    auto stage_write = [&](int c) {
        half_t* fb = frag + 16384 * (c & 1);
        #pragma unroll
        for (int i = 0; i < 8; i++) {
            const f32x4 v = vb[i];
            s  += v[0] + v[1] + v[2] + v[3];
            ss += v[0]*v[0] + v[1]*v[1] + v[2]*v[2] + v[3]*v[3];
            half4_t hv;
            hv[0] = (half_t)v[0]; hv[1] = (half_t)v[1];
            hv[2] = (half_t)v[2]; hv[3] = (half_t)v[3];
            const int hg = 2 * (i & 1) + (jj >> 1);
            *(half4_t*)(&fb[(((i >> 1) * 8 + rbw) * 64 + ((row & 15) + 16 * hg)) * 8 + 4 * (jj & 1)]) = hv;
        }
    };

    f32x4 acc0[8][4];
    #pragma unroll
    for (int rb = 0; rb < 8; rb++)
        #pragma unroll
        for (int cb = 0; cb < 4; cb++) acc0[rb][cb] = 0.f;

    // GEMM0 chunk: 4 t-steps, B double-buffered, A-frags in 2 halves (reg cap)
    auto gemm0 = [&](int c) {
        const half_t* fb = frag + 16384 * (c & 1);
        const half_t* wp = W0p + (size_t)(4 * wv * 24 + 4 * c) * 512 + lane * 8;
        half8_t bA[4], bB[4];
        #pragma unroll
        for (int cb = 0; cb < 4; cb++) bA[cb] = *(const half8_t*)(wp + cb * 12288);
        #pragma unroll
        for (int tt = 0; tt < 4; tt++) {
            half8_t* cur = (tt & 1) ? bB : bA;
            half8_t* nxt = (tt & 1) ? bA : bB;
            if (tt < 3) {
                #pragma unroll
                for (int cb = 0; cb < 4; cb++)
                    nxt[cb] = *(const half8_t*)(wp + (tt + 1) * 512 + cb * 12288);
            }
            #pragma unroll
            for (int rbh = 0; rbh < 2; rbh++) {
                half8_t af[4];
                #pragma unroll
                for (int rb = 0; rb < 4; rb++)
                    af[rb] = *(const half8_t*)(&fb[((tt * 8 + 4 * rbh + rb) * 64 + lane) * 8]);
                #pragma unroll
                for (int cb = 0; cb < 4; cb++)
                    #pragma unroll
                    for (int rb = 0; rb < 4; rb++)
                        acc0[4 * rbh + rb][cb] =
                            __builtin_amdgcn_mfma_f32_16x16x32_f16(af[rb], cur[cb], acc0[4 * rbh + rb][cb], 0, 0, 0);
            }
        }
    };

    // ---- pipeline: 6 chunks of K=128 ----
    stage_load(0); stage_write(0);
    __syncthreads();
    #pragma unroll 1
    for (int c = 0; c < 6; c++) {
        if (c < 5) stage_load(c + 1);     // HBM loads in flight during MFMA
        gemm0(c);
        if (c < 5) stage_write(c + 1);    // convert+LDS write after compute
        if (c == 4) {                     // all 6 chunks' stats accumulated
            s  += __shfl_xor(s, 1);  s  += __shfl_xor(s, 2);
            ss += __shfl_xor(ss, 1); ss += __shfl_xor(ss, 2);
            if (jj == 0) {
                const float mm = s * (1.f / 768.f);
                row_m[row]  = mm;
                row_rs[row] = 1.f / sqrtf(ss * (1.f / 768.f) - mm * mm + LN_EPS);
            }
        }
        __syncthreads();
    }

    // ---- epilogue0: LN0 fold + ELU + LN1 partials + x1 fragment writes ----
    {
        float sv[4], cv[4];
        #pragma unroll
        for (int cb = 0; cb < 4; cb++) {
            const int c = cl + 16 * (4 * wv + cb);
            sv[cb] = s0f[c]; cv[cb] = c0f[c];
        }
        #pragma unroll
        for (int rb = 0; rb < 8; rb++)
            #pragma unroll
            for (int v = 0; v < 4; v++) {
                const int r = 16 * rb + 4 * grp + v;
                const float rm = row_m[r], rr = row_rs[r];
                float a_ = 0.f, q_ = 0.f;
                #pragma unroll
                for (int cb = 0; cb < 4; cb++) {
                    float y = rr * (acc0[rb][cb][v] - rm * sv[cb]) + cv[cb];
                    y = y > 0.f ? y : (__expf(y) - 1.f);
                    acc0[rb][cb][v] = y;
                    a_ += y; q_ += y * y;
                }
                a_ += __shfl_xor(a_, 1); a_ += __shfl_xor(a_, 2); a_ += __shfl_xor(a_, 4); a_ += __shfl_xor(a_, 8);
                q_ += __shfl_xor(q_, 1); q_ += __shfl_xor(q_, 2); q_ += __shfl_xor(q_, 4); q_ += __shfl_xor(q_, 8);
                if (cl == 0) { psum[wv][r] = a_; psq[wv][r] = q_; }
            }
        #pragma unroll
        for (int cb = 0; cb < 4; cb++) {
            const int c = cl + 16 * (4 * wv + cb);
            const int t = c >> 5, j = c & 7, sc = 16 * ((c >> 3) & 3);
            #pragma unroll
            for (int rb = 0; rb < 8; rb++)
                #pragma unroll
                for (int v = 0; v < 4; v++)
                    frag[((t * 8 + rb) * 64 + (4 * grp + v + sc)) * 8 + j] = (half_t)acc0[rb][cb][v];
        }
    }
    __syncthreads();
    if (tid < 128) {
        float a_ = 0.f, q_ = 0.f;
        #pragma unroll
        for (int w = 0; w < 8; w++) { a_ += psum[w][tid]; q_ += psq[w][tid]; }
        const float mm = a_ * (1.f / 512.f);
        row_m[tid]  = mm;
        row_rs[tid] = 1.f / sqrtf(q_ * (1.f / 512.f) - mm * mm + LN_EPS);
    }
    __syncthreads();

    // ---- GEMM1: K=512 (16 t-steps), wave owns 32 cols, B prefetched ----
    f32x4 acc1[8][2];
    #pragma unroll
    for (int rb = 0; rb < 8; rb++) { acc1[rb][0] = 0.f; acc1[rb][1] = 0.f; }
    {
        const half_t* wp = W1p + (size_t)(2 * wv * 16) * 512 + lane * 8;
        half8_t bA[2], bB[2];
        bA[0] = *(const half8_t*)(wp);
        bA[1] = *(const half8_t*)(wp + 8192);
        #pragma unroll
        for (int t = 0; t < 16; t++) {
            half8_t* cur = (t & 1) ? bB : bA;
            half8_t* nxt = (t & 1) ? bA : bB;
            if (t < 15) {
                nxt[0] = *(const half8_t*)(wp + (t + 1) * 512);
                nxt[1] = *(const half8_t*)(wp + (t + 1) * 512 + 8192);
            }
            half8_t af[8];
            #pragma unroll
            for (int rb = 0; rb < 8; rb++)
                af[rb] = *(const half8_t*)(&frag[((t * 8 + rb) * 64 + lane) * 8]);
            #pragma unroll
            for (int cb = 0; cb < 2; cb++)
                #pragma unroll
                for (int rb = 0; rb < 8; rb++)
                    acc1[rb][cb] = __builtin_amdgcn_mfma_f32_16x16x32_f16(af[rb], cur[cb], acc1[rb][cb], 0, 0, 0);
        }
    }

    // ---- epilogue1: LN1 fold + ELU + LN2 partials (regs only) ----
    {
        float sv[2], cv[2];
        #pragma unroll
        for (int cb = 0; cb < 2; cb++) {
            const int c = cl + 16 * (2 * wv + cb);
            sv[cb] = s1f[c]; cv[cb] = c1f[c];
        }
        #pragma unroll
        for (int rb = 0; rb < 8; rb++)
            #pragma unroll
            for (int v = 0; v < 4; v++) {
                const int r = 16 * rb + 4 * grp + v;
                const float rm = row_m[r], rr = row_rs[r];
                float a_ = 0.f, q_ = 0.f;
                #pragma unroll
                for (int cb = 0; cb < 2; cb++) {
                    float y = rr * (acc1[rb][cb][v] - rm * sv[cb]) + cv[cb];
                    y = y > 0.f ? y : (__expf(y) - 1.f);
                    acc1[rb][cb][v] = y;
                    a_ += y; q_ += y * y;
                }
                a_ += __shfl_xor(a_, 1); a_ += __shfl_xor(a_, 2); a_ += __shfl_xor(a_, 4); a_ += __shfl_xor(a_, 8);
                q_ += __shfl_xor(q_, 1); q_ += __shfl_xor(q_, 2); q_ += __shfl_xor(q_, 4); q_ += __shfl_xor(q_, 8);
                if (cl == 0) { psum[wv][r] = a_; psq[wv][r] = q_; }
            }
    }
    __syncthreads();   // gemm1 readers done -> frag reusable; psum published
    // ---- x2 fragment writes + LN2 finalize ----
    #pragma unroll
    for (int cb = 0; cb < 2; cb++) {
        const int c = cl + 16 * (2 * wv + cb);
        const int t = c >> 5, j = c & 7, sc = 16 * ((c >> 3) & 3);
        #pragma unroll
        for (int rb = 0; rb < 8; rb++)
            #pragma unroll
            for (int v = 0; v < 4; v++)
                frag[((t * 8 + rb) * 64 + (4 * grp + v + sc)) * 8 + j] = (half_t)acc1[rb][cb][v];
    }
    if (tid < 128) {
        float a_ = 0.f, q_ = 0.f;
        #pragma unroll
        for (int w = 0; w < 8; w++) { a_ += psum[w][tid]; q_ += psq[w][tid]; }
        const float mm = a_ * (1.f / 256.f);
        row_m[tid]  = mm;
        row_rs[tid] = 1.f / sqrtf(q_ * (1.f / 256.f) - mm * mm + LN_EPS);
    }
    __syncthreads();

    // ---- GEMM2: K=256 (8 t-steps), wave owns 16 cols ----
    f32x4 acc2[8];
    #pragma unroll
    for (int rb = 0; rb < 8; rb++) acc2[rb] = 0.f;
    {
        const half_t* wp = W2p + (size_t)(wv * 8) * 512 + lane * 8;
        half8_t bA = *(const half8_t*)(wp);
        #pragma unroll
        for (int t = 0; t < 8; t++) {
            const half8_t cur = bA;
            if (t < 7) bA = *(const half8_t*)(wp + (t + 1) * 512);
            half8_t af[8];
            #pragma unroll
            for (int rb = 0; rb < 8; rb++)
                af[rb] = *(const half8_t*)(&frag[((t * 8 + rb) * 64 + lane) * 8]);
            #pragma unroll
            for (int rb = 0; rb < 8; rb++)
                acc2[rb] = __builtin_amdgcn_mfma_f32_16x16x32_f16(af[rb], cur, acc2[rb], 0, 0, 0);
        }
    }

    // ---- epilogue2: LN2 fold + ELU + LN3 partials + folded W3 dot ----
    {
        const int c2i = cl + 16 * wv;
        const float sv = s2f[c2i], cv = c2f[c2i], w3v = w3f[c2i];
        #pragma unroll
        for (int rb = 0; rb < 8; rb++)
            #pragma unroll
            for (int v = 0; v < 4; v++) {
                const int r = 16 * rb + 4 * grp + v;
                const float rm = row_m[r], rr = row_rs[r];
                float y = rr * (acc2[rb][v] - rm * sv) + cv;
                y = y > 0.f ? y : (__expf(y) - 1.f);
                float a_ = y, q_ = y * y, d_ = y * w3v;
                a_ += __shfl_xor(a_, 1); a_ += __shfl_xor(a_, 2); a_ += __shfl_xor(a_, 4); a_ += __shfl_xor(a_, 8);
                q_ += __shfl_xor(q_, 1); q_ += __shfl_xor(q_, 2); q_ += __shfl_xor(q_, 4); q_ += __shfl_xor(q_, 8);
                d_ += __shfl_xor(d_, 1); d_ += __shfl_xor(d_, 2); d_ += __shfl_xor(d_, 4); d_ += __shfl_xor(d_, 8);
                if (cl == 0) { psum[wv][r] = a_; psq[wv][r] = q_; pdot[wv][r] = d_; }
            }
    }
    __syncthreads();
    if (tid < 128) {
        float a_ = 0.f, q_ = 0.f, d_ = 0.f;
        #pragma unroll
        for (int w = 0; w < 8; w++) { a_ += psum[w][tid]; q_ += psq[w][tid]; d_ += pdot[w][tid]; }
        const float mm = a_ * (1.f / 128.f);
        const float rs = 1.f / sqrtf(q_ * (1.f / 128.f) - mm * mm + LN_EPS);
        out[r0 + tid] = rs * (d_ - mm * f[1920]) + f[1921];
    }
}

extern "C" void kernel_launch(void* const* d_in, const int* in_sizes, int n_in,
                              void* d_out, int out_size, void* d_ws, size_t ws_size,
                              hipStream_t stream) {
    const float* x  = (const float*)d_in[0];
    const float* g0 = (const float*)d_in[1];
    const float* b0 = (const float*)d_in[2];
    const float* W0 = (const float*)d_in[3];
    const float* c0 = (const float*)d_in[4];
    const float* g1 = (const float*)d_in[5];
    const float* b1 = (const float*)d_in[6];
    const float* W1 = (const float*)d_in[7];
    const float* c1 = (const float*)d_in[8];
    const float* g2 = (const float*)d_in[9];
    const float* b2 = (const float*)d_in[10];
    const float* W2 = (const float*)d_in[11];
    const float* c2 = (const float*)d_in[12];
    const float* g3 = (const float*)d_in[13];
    const float* b3 = (const float*)d_in[14];
    const float* W3 = (const float*)d_in[15];
    const float* c3 = (const float*)d_in[16];

    half_t* ws = (half_t*)d_ws;            // packed weights: 557056 halves
    float*  f  = (float*)(ws + 557056);    // folded scalars: 1922 floats

    pack_weights<<<272, 256, 0, stream>>>(W0, g0, W1, g1, W2, g2, ws);
    fold_bias<<<225, 256, 0, stream>>>(W0, g0, b0, c0, W1, g1, b1, c1,
                                       W2, g2, b2, c2, W3, g3, b3, c3, f);

    const int nrows = in_sizes[0] / 768;   // 262144
    fused_mlp<<<nrows / 128, 512, 0, stream>>>(
        x, ws, ws + 393216, ws + 524288, f, (float*)d_out);
}